// Round 7
// baseline (1831.166 us; speedup 1.0000x reference)
//
#include <hip/hip_runtime.h>
#include <stdint.h>
#include <stddef.h>

// GRU: T=512, B=64, F=128, H=512, O=16. fp32 in/out, bf16 MFMA compute.
//
// R15 = R13 (verified 1080us) + 2-way batch-group interleave using ONLY
// R13-proven primitives.
//  - Evidence: R13's step = 4900cy with ~1500cy compute -> ~3400cy spent in
//    4-5 serialized poll round-trips, because R13 polls ~300cy after its own
//    phase-aligned publish while publish->visible latency is ~2000-3000cy.
//  - Fix is DISTANCE, not in-flight overlap: each block owns two row-groups
//    A/B (same cg -> shared weights) and alternates full R13 sub-steps
//    A(t), B(t), A(t+1)... A's poll executes one whole B sub-step (~2200cy)
//    after the A-publishes -> first poll lands inside visibility window.
//  - Split-asm polling (issue one asm, wait in another) is BANNED: both
//    session container failures (R9, R14) introduced it; R10-R13 with the
//    combined issue+vmcnt(0)+check asm all ran clean. Everything here keeps
//    the combined pattern; x prefetch is a plain C load (R13-proven).
//  - LDS partials double-buffered BY GROUP: B's barrier separates A(t)'s
//    post-barrier reads from A(t+1)'s writes. One barrier per sub-step.
//  - All polls mguard-bounded: bugs fail, never hang.

#define T_LEN 512
#define B_SZ  64
#define F_DIM 128
#define H_DIM 512
#define O_DIM 16
#define SENTINEL 0xAAAAAAAAu

typedef __attribute__((ext_vector_type(8))) short short8;
typedef __attribute__((ext_vector_type(4))) float floatx4;
typedef __attribute__((ext_vector_type(4))) unsigned int uintx4;

#define MFMA16(a, b, c) __builtin_amdgcn_mfma_f32_16x16x32_bf16((a), (b), (c), 0, 0, 0)

__device__ __forceinline__ unsigned short f2bf(float f) {
  unsigned u = __builtin_bit_cast(unsigned, f);
  u += 0x7fffu + ((u >> 16) & 1u);   // round-to-nearest-even
  return (unsigned short)(u >> 16);
}

__device__ __forceinline__ float fastrcp(float d) {
  float r = __builtin_amdgcn_rcpf(d);
  return r * (2.0f - d * r);         // one NR step -> ~1 ulp
}

__device__ __forceinline__ float sigmoidf_(float x) {
  return fastrcp(1.0f + __expf(-x));
}

__device__ __forceinline__ float tanhf_(float x) {
  float v = fminf(fmaxf(x, -10.f), 10.f);
  float e = __expf(2.f * v);
  return (e - 1.f) * fastrcp(e + 1.f);
}

__device__ __forceinline__ short8 cvt8(floatx4 f0, floatx4 f1) {
  short8 a;
  a[0] = (short)f2bf(f0[0]); a[1] = (short)f2bf(f0[1]);
  a[2] = (short)f2bf(f0[2]); a[3] = (short)f2bf(f0[3]);
  a[4] = (short)f2bf(f1[0]); a[5] = (short)f2bf(f1[1]);
  a[6] = (short)f2bf(f1[2]); a[7] = (short)f2bf(f1[3]);
  return a;
}

// PROVEN pattern (R8/R13): 4 x dwordx4 sc1 loads + drain inside ONE asm.
__device__ __forceinline__ void hload4_sc1(floatx4* hf, const unsigned short* hbase) {
  asm volatile(
      "global_load_dwordx4 %0, %4, off sc1\n\t"
      "global_load_dwordx4 %1, %4, off offset:64 sc1\n\t"
      "global_load_dwordx4 %2, %4, off offset:128 sc1\n\t"
      "global_load_dwordx4 %3, %4, off offset:192 sc1\n\t"
      "s_waitcnt vmcnt(0)"
      : "=&v"(hf[0]), "=&v"(hf[1]), "=&v"(hf[2]), "=&v"(hf[3])
      : "v"(hbase)
      : "memory");
}

__device__ __forceinline__ bool clean4(const floatx4* hf) {
  bool ok = true;
  #pragma unroll
  for (int i = 0; i < 4; ++i) {
    uintx4 u = __builtin_bit_cast(uintx4, hf[i]);
    ok = ok & (u[0] != SENTINEL) & (u[1] != SENTINEL) &
         (u[2] != SENTINEL) & (u[3] != SENTINEL);
  }
  return __ballot(!ok) == 0ull;
}

__global__ __launch_bounds__(256, 1)
void gru_persistent2(const float* __restrict__ x,
                     const float* __restrict__ w_ih,
                     const float* __restrict__ w_hh,
                     const float* __restrict__ b_ih,
                     const float* __restrict__ b_hh,
                     unsigned short* __restrict__ hs) {  // (T,B,H) bf16, 0xAA-poisoned
  // partials: [group A/B][wave][row][col(+pad)][gate r,z,xn,hn]
  __shared__ __align__(16) float part[2][4][16][33][4];

  const int tid  = threadIdx.x;
  const int lane = tid & 63;
  const int wv   = tid >> 6;          // 0..3, each owns K-quarter wv
  const int cg   = blockIdx.x & 15;
  const int pair = blockIdx.x >> 4;   // 0..1
  const int bgA  = pair * 32;         // rows [bgA, bgA+16)
  const int bgB  = bgA + 16;          // rows [bgB, bgB+16)
  const int colbase = cg * 32;
  const int n16  = lane & 15;
  const int quad = lane >> 4;
  const floatx4 fz = {0.f, 0.f, 0.f, 0.f};

  // ---- preload W as bf16 MFMA B-fragments over MY K-quarter (shared A/B) ----
  short8 bwx[3][2];      // w_ih: K cols wv*32 + quad*8
  short8 bwh[3][2][4];   // w_hh: K cols wv*128 + i*32 + quad*8
  #pragma unroll
  for (int g = 0; g < 3; ++g) {
    #pragma unroll
    for (int nt = 0; nt < 2; ++nt) {
      const int grow = g * H_DIM + colbase + nt * 16 + n16;
      const float* pih = w_ih + (size_t)grow * F_DIM + wv * 32 + quad * 8;
      {
        short8 v;
        #pragma unroll
        for (int j = 0; j < 8; ++j) v[j] = (short)f2bf(pih[j]);
        bwx[g][nt] = v;
      }
      const float* phh = w_hh + (size_t)grow * H_DIM + wv * 128 + quad * 8;
      #pragma unroll
      for (int i = 0; i < 4; ++i) {
        short8 v;
        #pragma unroll
        for (int j = 0; j < 8; ++j) v[j] = (short)f2bf(phh[i * 32 + j]);
        bwh[g][nt][i] = v;
      }
    }
  }

  const int ew_b  = tid >> 4;          // elementwise row 0..15
  const int ew_j0 = (tid & 15) * 2;    // first of 2 adjacent owned cols
  float b_rz[2], b_zz[2], b_in[2], b_hn[2];
  #pragma unroll
  for (int e = 0; e < 2; ++e) {
    const int c = colbase + ew_j0 + e;
    b_rz[e] = b_ih[c] + b_hh[c];
    b_zz[e] = b_ih[H_DIM + c] + b_hh[H_DIM + c];
    b_in[e] = b_ih[2 * H_DIM + c];
    b_hn[e] = b_hh[2 * H_DIM + c];
  }
  float hmA[2] = {0.f, 0.f}, hmB[2] = {0.f, 0.f};  // fp32 carries (registers)

  // x(0) for both groups (plain loads, pre-loop)
  floatx4 xfA0, xfA1, xfB0, xfB1;
  {
    const float* pa = x + ((size_t)(bgA + n16)) * F_DIM + wv * 32 + quad * 8;
    xfA0 = *(const floatx4*)pa; xfA1 = *(const floatx4*)(pa + 4);
    const float* pb = x + ((size_t)(bgB + n16)) * F_DIM + wv * 32 + quad * 8;
    xfB0 = *(const floatx4*)pb; xfB1 = *(const floatx4*)(pb + 4);
  }

  floatx4 acc[8];          // [R0,R1,Z0,Z1,X0,X1,H0,H1] — reused by A and B
  floatx4 hf[4];           // poll buffer — reused by A and B
  int mguard = 1 << 18;    // anti-hang poll budget (bugs fail, never hang)

  auto xpart = [&](short8 a) {
    acc[0] = MFMA16(a, bwx[0][0], fz); acc[1] = MFMA16(a, bwx[0][1], fz);
    acc[2] = MFMA16(a, bwx[1][0], fz); acc[3] = MFMA16(a, bwx[1][1], fz);
    acc[4] = MFMA16(a, bwx[2][0], fz); acc[5] = MFMA16(a, bwx[2][1], fz);
    acc[6] = fz; acc[7] = fz;
  };
  auto hpart = [&]() {
    #pragma unroll
    for (int i = 0; i < 4; ++i) {
      short8 a = __builtin_bit_cast(short8, hf[i]);
      acc[0] = MFMA16(a, bwh[0][0][i], acc[0]); acc[1] = MFMA16(a, bwh[0][1][i], acc[1]);
      acc[2] = MFMA16(a, bwh[1][0][i], acc[2]); acc[3] = MFMA16(a, bwh[1][1][i], acc[3]);
      acc[6] = MFMA16(a, bwh[2][0][i], acc[6]); acc[7] = MFMA16(a, bwh[2][1][i], acc[7]);
    }
  };
  // LDS partials + barrier + reduce + gates + relaxed sc1 publish (R13-exact)
  auto epilogue = [&](int pb, int bgbase, float* hm2, int t) {
    #pragma unroll
    for (int i = 0; i < 4; ++i) {
      const int r = quad * 4 + i;
      floatx4 v0 = {acc[0][i], acc[2][i], acc[4][i], acc[6][i]};
      floatx4 v1 = {acc[1][i], acc[3][i], acc[5][i], acc[7][i]};
      *(floatx4*)&part[pb][wv][r][n16][0]      = v0;
      *(floatx4*)&part[pb][wv][r][16 + n16][0] = v1;
    }
    __syncthreads();   // one barrier per sub-step: part[pb] ready
    float pr[2] = {0.f, 0.f}, pz[2] = {0.f, 0.f};
    float pn[2] = {0.f, 0.f}, ph[2] = {0.f, 0.f};
    #pragma unroll
    for (int w = 0; w < 4; ++w) {
      #pragma unroll
      for (int e = 0; e < 2; ++e) {
        floatx4 g = *(const floatx4*)&part[pb][w][ew_b][ew_j0 + e][0];
        pr[e] += g[0]; pz[e] += g[1]; pn[e] += g[2]; ph[e] += g[3];
      }
    }
    unsigned short hb2[2];
    #pragma unroll
    for (int e = 0; e < 2; ++e) {
      const float r = sigmoidf_(pr[e] + b_rz[e]);
      const float z = sigmoidf_(pz[e] + b_zz[e]);
      const float n = tanhf_(pn[e] + b_in[e] + r * (ph[e] + b_hn[e]));
      const float hn2 = (1.0f - z) * n + z * hm2[e];
      hm2[e] = hn2;
      hb2[e] = f2bf(hn2);
    }
    const unsigned int packed = ((unsigned int)hb2[1] << 16) | (unsigned int)hb2[0];
    unsigned int* dst = (unsigned int*)(hs +
        ((size_t)(t * B_SZ + bgbase + ew_b)) * H_DIM + colbase + ew_j0);
    __hip_atomic_store(dst, packed, __ATOMIC_RELAXED, __HIP_MEMORY_SCOPE_AGENT);
  };

  // ---- t=0 peeled: x-only, h0 = 0, both groups ----
  xpart(cvt8(xfA0, xfA1));
  {
    const float* p = x + ((size_t)(B_SZ + bgA + n16)) * F_DIM + wv * 32 + quad * 8;
    xfA0 = *(const floatx4*)p; xfA1 = *(const floatx4*)(p + 4);
  }
  epilogue(0, bgA, hmA, 0);

  xpart(cvt8(xfB0, xfB1));
  {
    const float* p = x + ((size_t)(B_SZ + bgB + n16)) * F_DIM + wv * 32 + quad * 8;
    xfB0 = *(const floatx4*)p; xfB1 = *(const floatx4*)(p + 4);
  }
  epilogue(1, bgB, hmB, 0);

  // ---- main loop: each superstep advances BOTH groups one t (A then B).
  // A's publish->poll distance = one full B sub-step (~2200cy); B's likewise.
  for (int t = 1; t < T_LEN; ++t) {
    // ======== A sub-step (R13-exact protocol) ========
    {
      xpart(cvt8(xfA0, xfA1));   // settling delay + x-part
      const unsigned short* hb =
          hs + ((size_t)((t - 1) * B_SZ + bgA + n16)) * H_DIM + wv * 128 + quad * 8;
      while (true) {             // the load IS the poll (combined asm)
        hload4_sc1(hf, hb);
        if (clean4(hf)) break;
        if (--mguard <= 0) break;
      }
      if (t + 1 < T_LEN) {       // x(t+1) prefetch, plain C (compiler-managed)
        const float* p = x + ((size_t)((t + 1) * B_SZ + bgA + n16)) * F_DIM +
                         wv * 32 + quad * 8;
        xfA0 = *(const floatx4*)p; xfA1 = *(const floatx4*)(p + 4);
      }
      hpart();
      epilogue(0, bgA, hmA, t);
    }
    // ======== B sub-step ========
    {
      xpart(cvt8(xfB0, xfB1));
      const unsigned short* hb =
          hs + ((size_t)((t - 1) * B_SZ + bgB + n16)) * H_DIM + wv * 128 + quad * 8;
      while (true) {
        hload4_sc1(hf, hb);
        if (clean4(hf)) break;
        if (--mguard <= 0) break;
      }
      if (t + 1 < T_LEN) {
        const float* p = x + ((size_t)((t + 1) * B_SZ + bgB + n16)) * F_DIM +
                         wv * 32 + quad * 8;
        xfB0 = *(const floatx4*)p; xfB1 = *(const floatx4*)(p + 4);
      }
      hpart();
      epilogue(1, bgB, hmB, t);
    }
  }
}

// y = hs @ w_out^T + b_out : M=32768, N=16, K=512; 4 row-tiles per wg (1/wave)
__global__ __launch_bounds__(256, 1)
void gru_proj(const unsigned short* __restrict__ hs,
              const float* __restrict__ w_out,
              const float* __restrict__ b_out,
              float* __restrict__ y) {
  const int tid  = threadIdx.x;
  const int lane = tid & 63;
  const int wv   = tid >> 6;
  const int n16  = lane & 15;
  const int quad = lane >> 4;
  const size_t rowbase = ((size_t)blockIdx.x * 4 + wv) * 16;

  short8 bw[16];
  const float* pw = w_out + (size_t)n16 * H_DIM + quad * 8;
  #pragma unroll
  for (int kc = 0; kc < 16; ++kc) {
    short8 v;
    #pragma unroll
    for (int j = 0; j < 8; ++j) v[j] = (short)f2bf(pw[kc * 32 + j]);
    bw[kc] = v;
  }
  const float bo = b_out[n16];

  const unsigned short* hbase = hs + (rowbase + n16) * H_DIM + quad * 8;
  floatx4 acc = {0.f, 0.f, 0.f, 0.f};
  #pragma unroll
  for (int kc = 0; kc < 16; ++kc) {
    short8 a = *(const short8*)(hbase + kc * 32);
    acc = MFMA16(a, bw[kc], acc);
  }
  #pragma unroll
  for (int i = 0; i < 4; ++i) {
    const size_t r = rowbase + quad * 4 + i;
    y[r * O_DIM + n16] = acc[i] + bo;
  }
}

extern "C" void kernel_launch(void* const* d_in, const int* in_sizes, int n_in,
                              void* d_out, int out_size, void* d_ws, size_t ws_size,
                              hipStream_t stream) {
  (void)in_sizes; (void)n_in; (void)out_size; (void)ws_size;
  const float* x     = (const float*)d_in[0];
  const float* w_ih  = (const float*)d_in[1];
  const float* w_hh  = (const float*)d_in[2];
  const float* b_ih  = (const float*)d_in[3];
  const float* b_hh  = (const float*)d_in[4];
  const float* w_out = (const float*)d_in[5];
  const float* b_out = (const float*)d_in[6];
  float* y = (float*)d_out;

  // hs: 32 MB bf16 history in d_ws; harness 0xAA-poison IS the sentinel.
  unsigned short* hs = (unsigned short*)d_ws;

  // 32 interleaved recurrence blocks (2 bg-groups each), then projection.
  gru_persistent2<<<32, 256, 0, stream>>>(x, w_ih, w_hh, b_ih, b_hh, hs);
  gru_proj<<<(T_LEN * B_SZ) / 16 / 4, 256, 0, stream>>>(hs, w_out, b_out, y);
}

// Round 8
// 1643.279 us; speedup vs baseline: 1.1143x; 1.1143x over previous
//
#include <hip/hip_runtime.h>
#include <stdint.h>
#include <stddef.h>

// GRU: T=512, B=64, F=128, H=512, O=16. fp32 in/out, bf16 MFMA compute.
//
// R16 = R13 skeleton (verified 1080us; 64 recurrence blocks, R8 exchange
// protocol, conflict-free LDS partials, fastrcp gates, separate proj) + the
// L2-mailbox fast path, built from R12's negative result:
//  - R12 proved sc0 polls are served by the local XCD L2 (FETCH collapsed)
//    but sc1 publishes BYPASS that L2 -> sc0 read stale. Fix: DUAL publish.
//    Each h dword is stored twice: __hip_atomic_store agent/sc1 (to LLC:
//    correctness, fallback, proj) AND a plain global_store_dword (lands in
//    the producer XCD's L2: the fast path). Same value both paths -> no
//    corruption regardless of writeback order.
//  - bg-group co-location: grid 128, active iff blockIdx%8 < 4; bg =
//    blockIdx%8, cg = blockIdx>>3. Empirically XCD = blockIdx%8, so all 16
//    blocks of a bg-group (the ONLY blocks that exchange h) share one XCD L2.
//    sc0 poll visibility ~200cy + RT ~300cy vs sc1's ~1700cy+.
//  - Adaptive guard (tightened R12): sc0 fast poll up to 3 tries then proven
//    sc1 poll; fast path must win >=3 of steps 1..6 or it is disabled for
//    the rest. Wrong placement => ~2us wasted, exact R13 behavior after.
//  - All polls are combined issue+vmcnt(0)+check single-asm (split-asm
//    banned: both session container failures R9/R14 used it). Per-dword
//    sentinel checks; mguard-bounded: bugs fail, never hang.
//  - R15 lesson recorded: chains are block-parallel; single-stream
//    interleaving (stall + 2x compute) can never beat 64 blocks (stall + 1x).

#define T_LEN 512
#define B_SZ  64
#define F_DIM 128
#define H_DIM 512
#define O_DIM 16
#define SENTINEL 0xAAAAAAAAu

typedef __attribute__((ext_vector_type(8))) short short8;
typedef __attribute__((ext_vector_type(4))) float floatx4;
typedef __attribute__((ext_vector_type(4))) unsigned int uintx4;

#define MFMA16(a, b, c) __builtin_amdgcn_mfma_f32_16x16x32_bf16((a), (b), (c), 0, 0, 0)

__device__ __forceinline__ unsigned short f2bf(float f) {
  unsigned u = __builtin_bit_cast(unsigned, f);
  u += 0x7fffu + ((u >> 16) & 1u);   // round-to-nearest-even
  return (unsigned short)(u >> 16);
}

__device__ __forceinline__ float fastrcp(float d) {
  float r = __builtin_amdgcn_rcpf(d);
  return r * (2.0f - d * r);         // one NR step -> ~1 ulp
}

__device__ __forceinline__ float sigmoidf_(float x) {
  return fastrcp(1.0f + __expf(-x));
}

__device__ __forceinline__ float tanhf_(float x) {
  float v = fminf(fmaxf(x, -10.f), 10.f);
  float e = __expf(2.f * v);
  return (e - 1.f) * fastrcp(e + 1.f);
}

__device__ __forceinline__ short8 cvt8(floatx4 f0, floatx4 f1) {
  short8 a;
  a[0] = (short)f2bf(f0[0]); a[1] = (short)f2bf(f0[1]);
  a[2] = (short)f2bf(f0[2]); a[3] = (short)f2bf(f0[3]);
  a[4] = (short)f2bf(f1[0]); a[5] = (short)f2bf(f1[1]);
  a[6] = (short)f2bf(f1[2]); a[7] = (short)f2bf(f1[3]);
  return a;
}

// PROVEN (R8/R13): 4 x dwordx4 sc1 loads + drain inside ONE asm (LLC path).
__device__ __forceinline__ void hload4_sc1(floatx4* hf, const unsigned short* hbase) {
  asm volatile(
      "global_load_dwordx4 %0, %4, off sc1\n\t"
      "global_load_dwordx4 %1, %4, off offset:64 sc1\n\t"
      "global_load_dwordx4 %2, %4, off offset:128 sc1\n\t"
      "global_load_dwordx4 %3, %4, off offset:192 sc1\n\t"
      "s_waitcnt vmcnt(0)"
      : "=&v"(hf[0]), "=&v"(hf[1]), "=&v"(hf[2]), "=&v"(hf[3])
      : "v"(hbase)
      : "memory");
}

// Fast path (ran fine in R12): sc0 loads -- L1-bypass, served by local XCD L2.
__device__ __forceinline__ void hload4_sc0(floatx4* hf, const unsigned short* hbase) {
  asm volatile(
      "global_load_dwordx4 %0, %4, off sc0\n\t"
      "global_load_dwordx4 %1, %4, off offset:64 sc0\n\t"
      "global_load_dwordx4 %2, %4, off offset:128 sc0\n\t"
      "global_load_dwordx4 %3, %4, off offset:192 sc0\n\t"
      "s_waitcnt vmcnt(0)"
      : "=&v"(hf[0]), "=&v"(hf[1]), "=&v"(hf[2]), "=&v"(hf[3])
      : "v"(hbase)
      : "memory");
}

__device__ __forceinline__ bool clean4(const floatx4* hf) {
  bool ok = true;
  #pragma unroll
  for (int i = 0; i < 4; ++i) {
    uintx4 u = __builtin_bit_cast(uintx4, hf[i]);
    ok = ok & (u[0] != SENTINEL) & (u[1] != SENTINEL) &
         (u[2] != SENTINEL) & (u[3] != SENTINEL);
  }
  return __ballot(!ok) == 0ull;
}

__global__ __launch_bounds__(256, 1)
void gru_persistent(const float* __restrict__ x,
                    const float* __restrict__ w_ih,
                    const float* __restrict__ w_hh,
                    const float* __restrict__ b_ih,
                    const float* __restrict__ b_hh,
                    unsigned short* __restrict__ hs) {  // (T, B, H) bf16, 0xAA-poisoned
  // Placement: active iff blockIdx%8 < 4 (empirical XCD id = blockIdx%8).
  // bg = XCD -> all 16 exchanging blocks of a bg-group share one L2.
  const int slot = (int)blockIdx.x & 7;
  if (slot >= 4) return;               // XCDs 4..7: no-op blocks

  // partials: [buf][wave][row][col(+pad)][gate r,z,xn,hn] -- b128 both sides
  __shared__ __align__(16) float part[2][4][16][33][4];

  const int tid  = threadIdx.x;
  const int lane = tid & 63;
  const int wv   = tid >> 6;          // 0..3, each owns K-quarter wv
  const int bg   = slot;
  const int cg   = (int)blockIdx.x >> 3;
  const int bgbase  = bg * 16;
  const int colbase = cg * 32;
  const int n16  = lane & 15;
  const int quad = lane >> 4;

  // ---- preload W as bf16 MFMA B-fragments over MY K-quarter (read once) ----
  short8 bwx[3][2];      // w_ih: K cols wv*32 + quad*8
  short8 bwh[3][2][4];   // w_hh: K cols wv*128 + i*32 + quad*8
  #pragma unroll
  for (int g = 0; g < 3; ++g) {
    #pragma unroll
    for (int nt = 0; nt < 2; ++nt) {
      const int grow = g * H_DIM + colbase + nt * 16 + n16;
      const float* pih = w_ih + (size_t)grow * F_DIM + wv * 32 + quad * 8;
      {
        short8 v;
        #pragma unroll
        for (int j = 0; j < 8; ++j) v[j] = (short)f2bf(pih[j]);
        bwx[g][nt] = v;
      }
      const float* phh = w_hh + (size_t)grow * H_DIM + wv * 128 + quad * 8;
      #pragma unroll
      for (int i = 0; i < 4; ++i) {
        short8 v;
        #pragma unroll
        for (int j = 0; j < 8; ++j) v[j] = (short)f2bf(phh[i * 32 + j]);
        bwh[g][nt][i] = v;
      }
    }
  }

  const int ew_b  = tid >> 4;          // elementwise row 0..15
  const int ew_j0 = (tid & 15) * 2;    // first of 2 adjacent owned cols
  float b_rz[2], b_zz[2], b_in[2], b_hn[2];
  #pragma unroll
  for (int e = 0; e < 2; ++e) {
    const int c = colbase + ew_j0 + e;
    b_rz[e] = b_ih[c] + b_hh[c];
    b_zz[e] = b_ih[H_DIM + c] + b_hh[H_DIM + c];
    b_in[e] = b_ih[2 * H_DIM + c];
    b_hn[e] = b_hh[2 * H_DIM + c];
  }
  float hm[2] = {0.0f, 0.0f};   // fp32 master h carry: thread-private registers

  // ---- x fp32 regs for step t (my 32-col K-slice), loaded during step t-1 ----
  floatx4 xf0, xf1;
  {
    const float* px = x + ((size_t)(bgbase + n16)) * F_DIM + wv * 32 + quad * 8;
    xf0 = *(const floatx4*)px;
    xf1 = *(const floatx4*)(px + 4);
  }

  int mguard  = 1 << 18;  // shared anti-hang poll budget (bugs fail, never hang)
  int use_sc0 = 1;        // adaptive L2-mailbox fast path
  int s0wins  = 0;

  for (int t = 0; t < T_LEN; ++t) {
    // ---- x-part of this step's partials (also producer-settling delay) ----
    floatx4 aR0 = {0.f,0.f,0.f,0.f}, aR1 = {0.f,0.f,0.f,0.f};
    floatx4 aZ0 = {0.f,0.f,0.f,0.f}, aZ1 = {0.f,0.f,0.f,0.f};
    floatx4 aX0 = {0.f,0.f,0.f,0.f}, aX1 = {0.f,0.f,0.f,0.f};
    floatx4 aH0 = {0.f,0.f,0.f,0.f}, aH1 = {0.f,0.f,0.f,0.f};
    {
      short8 a = cvt8(xf0, xf1);
      aR0 = MFMA16(a, bwx[0][0], aR0); aR1 = MFMA16(a, bwx[0][1], aR1);
      aZ0 = MFMA16(a, bwx[1][0], aZ0); aZ1 = MFMA16(a, bwx[1][1], aZ1);
      aX0 = MFMA16(a, bwx[2][0], aX0); aX1 = MFMA16(a, bwx[2][1], aX1);
    }

    if (t > 0) {
      // ---- data-poll of my K-quarter of h(t-1): sc0 fast path, sc1 proven ----
      floatx4 hf[4];
      {
        const unsigned short* hbase =
            hs + ((size_t)((t - 1) * B_SZ + bgbase + n16)) * H_DIM + wv * 128 + quad * 8;
        bool won0 = false;
        int tries = use_sc0 ? 3 : 0;
        while (true) {
          if (tries > 0) {
            --tries;
            hload4_sc0(hf, hbase);          // same-XCD L2 mailbox (~300cy)
            if (clean4(hf)) { won0 = true; break; }
          } else {
            hload4_sc1(hf, hbase);          // proven LLC path
            if (clean4(hf)) break;
          }
          if (--mguard <= 0) break;
        }
        if (t <= 6) {
          s0wins += (int)won0;
          if (t == 6 && s0wins < 3) use_sc0 = 0;   // placement didn't cooperate
        }
      }
      // ---- issue x loads for t+1 (latency hides under h-MFMA+elementwise) ----
      if (t + 1 < T_LEN) {
        const float* px = x + ((size_t)((t + 1) * B_SZ + bgbase + n16)) * F_DIM +
                          wv * 32 + quad * 8;
        xf0 = *(const floatx4*)px;
        xf1 = *(const floatx4*)(px + 4);
      }
      // ---- h-part MFMAs over my K-quarter (r, z, hn) ----
      #pragma unroll
      for (int i = 0; i < 4; ++i) {
        short8 a = __builtin_bit_cast(short8, hf[i]);
        aR0 = MFMA16(a, bwh[0][0][i], aR0); aR1 = MFMA16(a, bwh[0][1][i], aR1);
        aZ0 = MFMA16(a, bwh[1][0][i], aZ0); aZ1 = MFMA16(a, bwh[1][1][i], aZ1);
        aH0 = MFMA16(a, bwh[2][0][i], aH0); aH1 = MFMA16(a, bwh[2][1][i], aH1);
      }
    } else {
      // t == 0: no h yet; prefetch x for t=1
      const float* px = x + ((size_t)(B_SZ + bgbase + n16)) * F_DIM + wv * 32 + quad * 8;
      xf0 = *(const floatx4*)px;
      xf1 = *(const floatx4*)(px + 4);
    }

    // ---- write my partials, b128, conflict-free layout ----
    {
      const int tb = t & 1;
      #pragma unroll
      for (int i = 0; i < 4; ++i) {
        const int r = quad * 4 + i;
        floatx4 v0 = {aR0[i], aZ0[i], aX0[i], aH0[i]};
        floatx4 v1 = {aR1[i], aZ1[i], aX1[i], aH1[i]};
        *(floatx4*)&part[tb][wv][r][n16][0]      = v0;
        *(floatx4*)&part[tb][wv][r][16 + n16][0] = v1;
      }
    }
    __syncthreads();   // the ONE barrier per step: part[t&1] ready

    // ---- fused gate elementwise: sum 4 partials; 2 (b,col) items/thread ----
    {
      const int tb = t & 1;
      float pr[2] = {0.f, 0.f}, pz[2] = {0.f, 0.f};
      float pn[2] = {0.f, 0.f}, ph[2] = {0.f, 0.f};
      #pragma unroll
      for (int w = 0; w < 4; ++w) {
        #pragma unroll
        for (int e = 0; e < 2; ++e) {
          floatx4 g = *(const floatx4*)&part[tb][w][ew_b][ew_j0 + e][0];
          pr[e] += g[0]; pz[e] += g[1]; pn[e] += g[2]; ph[e] += g[3];
        }
      }
      unsigned short hb[2];
      #pragma unroll
      for (int e = 0; e < 2; ++e) {
        const float r = sigmoidf_(pr[e] + b_rz[e]);
        const float z = sigmoidf_(pz[e] + b_zz[e]);
        const float n = tanhf_(pn[e] + b_in[e] + r * (ph[e] + b_hn[e]));
        const float hn2 = (1.0f - z) * n + z * hm[e];
        hm[e] = hn2;   // fp32 carry path in registers
        hb[e] = f2bf(hn2);
      }
      const unsigned int packed = ((unsigned int)hb[1] << 16) | (unsigned int)hb[0];
      unsigned int* dst = (unsigned int*)(hs +
          ((size_t)(t * B_SZ + bgbase + ew_b)) * H_DIM + colbase + ew_j0);
      // DUAL publish, both fire-and-forget:
      //  1. sc1 (agent) -> LLC: correctness, sc1 fallback pollers, proj.
      __hip_atomic_store(dst, packed, __ATOMIC_RELAXED, __HIP_MEMORY_SCOPE_AGENT);
      //  2. plain -> local XCD L2: the sc0 fast path's source of truth.
      asm volatile("global_store_dword %0, %1, off"
                   :: "v"(dst), "v"(packed) : "memory");
    }
    // no second barrier: partials double-buffered, h carry in registers
  }
}

// y = hs @ w_out^T + b_out : M=32768, N=16, K=512; 4 row-tiles per wg (1/wave)
__global__ __launch_bounds__(256, 1)
void gru_proj(const unsigned short* __restrict__ hs,
              const float* __restrict__ w_out,
              const float* __restrict__ b_out,
              float* __restrict__ y) {
  const int tid  = threadIdx.x;
  const int lane = tid & 63;
  const int wv   = tid >> 6;
  const int n16  = lane & 15;
  const int quad = lane >> 4;
  const size_t rowbase = ((size_t)blockIdx.x * 4 + wv) * 16;

  short8 bw[16];
  const float* pw = w_out + (size_t)n16 * H_DIM + quad * 8;
  #pragma unroll
  for (int kc = 0; kc < 16; ++kc) {
    short8 v;
    #pragma unroll
    for (int j = 0; j < 8; ++j) v[j] = (short)f2bf(pw[kc * 32 + j]);
    bw[kc] = v;
  }
  const float bo = b_out[n16];

  const unsigned short* hbase = hs + (rowbase + n16) * H_DIM + quad * 8;
  floatx4 acc = {0.f, 0.f, 0.f, 0.f};
  #pragma unroll
  for (int kc = 0; kc < 16; ++kc) {
    short8 a = *(const short8*)(hbase + kc * 32);
    acc = MFMA16(a, bw[kc], acc);
  }
  #pragma unroll
  for (int i = 0; i < 4; ++i) {
    const size_t r = rowbase + quad * 4 + i;
    y[r * O_DIM + n16] = acc[i] + bo;
  }
}

extern "C" void kernel_launch(void* const* d_in, const int* in_sizes, int n_in,
                              void* d_out, int out_size, void* d_ws, size_t ws_size,
                              hipStream_t stream) {
  (void)in_sizes; (void)n_in; (void)out_size; (void)ws_size;
  const float* x     = (const float*)d_in[0];
  const float* w_ih  = (const float*)d_in[1];
  const float* w_hh  = (const float*)d_in[2];
  const float* b_ih  = (const float*)d_in[3];
  const float* b_hh  = (const float*)d_in[4];
  const float* w_out = (const float*)d_in[5];
  const float* b_out = (const float*)d_in[6];
  float* y = (float*)d_out;

  // hs: 32 MB bf16 history in d_ws. The harness poisons d_ws with 0xAA before
  // every launch — that poison IS our "not yet written" sentinel. No memset.
  unsigned short* hs = (unsigned short*)d_ws;

  // Grid 128: blocks with blockIdx%8>=4 exit immediately; the 64 active
  // blocks give each bg-group one XCD-local L2 mailbox. Proj unchanged
  // (separate dispatch sees all writes via end-of-dispatch release).
  gru_persistent<<<128, 256, 0, stream>>>(x, w_ih, w_hh, b_ih, b_hh, hs);
  gru_proj<<<(T_LEN * B_SZ) / 16 / 4, 256, 0, stream>>>(hs, w_out, b_out, y);
}

// Round 9
// 1075.221 us; speedup vs baseline: 1.7031x; 1.5283x over previous
//
#include <hip/hip_runtime.h>
#include <stdint.h>
#include <stddef.h>

// GRU: T=512, B=64, F=128, H=512, O=16. fp32 in/out, bf16 MFMA compute.
//
// R17 = R13 (champion, 1080us) with ONE flag change, from counter forensics:
//  - R13's FETCH (215MB) << one-attempt poll traffic (524MB) => most poll
//    retries were served by STALE L1 lines (sc1-only loads bypass L2, not L1).
//    Each stale hit wastes a full retry quantum on the critical path and is a
//    latent mguard-exhaustion hazard. Fix: poll loads use "sc0 sc1" (bypass
//    L1 AND L2 -> every attempt LLC-fresh). Diagnostic: FETCH should RISE
//    toward ~300MB while dur drops; FETCH up + dur flat falsifies the theory.
//  - Everything else byte-identical to R13: 64 recurrence blocks, x-MFMA
//    settle -> combined issue+vmcnt(0)+check poll (split-asm banned: R9/R14
//    both died with it), relaxed agent-scope publish, conflict-free LDS
//    partials (8.4M->0 verified), fastrcp gates, separate proj dispatch.
// REJECTED by measurement: early poll (R10 +274us), atomic-swap publish
// (R11 +164us), sc0-only XCD mailbox (R12 +425us, R16 +563us + 71ms outlier),
// single-stream 2-chain interleave (R15 +690us: stall + 2x compute always
// loses to block-parallel chains at stall + 1x compute).

#define T_LEN 512
#define B_SZ  64
#define F_DIM 128
#define H_DIM 512
#define O_DIM 16
#define SENTINEL 0xAAAAAAAAu

typedef __attribute__((ext_vector_type(8))) short short8;
typedef __attribute__((ext_vector_type(4))) float floatx4;
typedef __attribute__((ext_vector_type(4))) unsigned int uintx4;

__device__ __forceinline__ unsigned short f2bf(float f) {
  unsigned u = __builtin_bit_cast(unsigned, f);
  u += 0x7fffu + ((u >> 16) & 1u);   // round-to-nearest-even
  return (unsigned short)(u >> 16);
}

__device__ __forceinline__ float fastrcp(float d) {
  float r = __builtin_amdgcn_rcpf(d);
  return r * (2.0f - d * r);         // one NR step -> ~1 ulp
}

__device__ __forceinline__ float sigmoidf_(float x) {
  return fastrcp(1.0f + __expf(-x));
}

__device__ __forceinline__ float tanhf_(float x) {
  float v = fminf(fmaxf(x, -10.f), 10.f);
  float e = __expf(2.f * v);
  return (e - 1.f) * fastrcp(e + 1.f);
}

__device__ __forceinline__ short8 cvt8(floatx4 f0, floatx4 f1) {
  short8 a;
  a[0] = (short)f2bf(f0[0]); a[1] = (short)f2bf(f0[1]);
  a[2] = (short)f2bf(f0[2]); a[3] = (short)f2bf(f0[3]);
  a[4] = (short)f2bf(f1[0]); a[5] = (short)f2bf(f1[1]);
  a[6] = (short)f2bf(f1[2]); a[7] = (short)f2bf(f1[3]);
  return a;
}

// Poll: 4 x dwordx4 fully-coherent loads (sc0 sc1 = bypass L1 AND L2, always
// LLC-fresh) + drain, inside ONE asm (proven combined pattern).
__device__ __forceinline__ void hload4_llc(floatx4* hf, const unsigned short* hbase) {
  asm volatile(
      "global_load_dwordx4 %0, %4, off sc0 sc1\n\t"
      "global_load_dwordx4 %1, %4, off offset:64 sc0 sc1\n\t"
      "global_load_dwordx4 %2, %4, off offset:128 sc0 sc1\n\t"
      "global_load_dwordx4 %3, %4, off offset:192 sc0 sc1\n\t"
      "s_waitcnt vmcnt(0)"
      : "=&v"(hf[0]), "=&v"(hf[1]), "=&v"(hf[2]), "=&v"(hf[3])
      : "v"(hbase)
      : "memory");
}

__global__ __launch_bounds__(256, 1)
void gru_persistent(const float* __restrict__ x,
                    const float* __restrict__ w_ih,
                    const float* __restrict__ w_hh,
                    const float* __restrict__ b_ih,
                    const float* __restrict__ b_hh,
                    unsigned short* __restrict__ hs) {  // (T, B, H) bf16, 0xAA-poisoned
  // partials: [buf][wave][row][col(+pad)][gate r,z,xn,hn] -- b128 both sides
  __shared__ __align__(16) float part[2][4][16][33][4];

  const int tid  = threadIdx.x;
  const int lane = tid & 63;
  const int wv   = tid >> 6;          // 0..3, each owns K-quarter wv
  const int bg   = blockIdx.x >> 4;
  const int cg   = blockIdx.x & 15;
  const int bgbase  = bg * 16;
  const int colbase = cg * 32;
  const int n16  = lane & 15;
  const int quad = lane >> 4;

  // ---- preload W as bf16 MFMA B-fragments over MY K-quarter (read once) ----
  short8 bwx[3][2];      // w_ih: K cols wv*32 + quad*8
  short8 bwh[3][2][4];   // w_hh: K cols wv*128 + i*32 + quad*8
  #pragma unroll
  for (int g = 0; g < 3; ++g) {
    #pragma unroll
    for (int nt = 0; nt < 2; ++nt) {
      const int grow = g * H_DIM + colbase + nt * 16 + n16;
      const float* pih = w_ih + (size_t)grow * F_DIM + wv * 32 + quad * 8;
      {
        short8 v;
        #pragma unroll
        for (int j = 0; j < 8; ++j) v[j] = (short)f2bf(pih[j]);
        bwx[g][nt] = v;
      }
      const float* phh = w_hh + (size_t)grow * H_DIM + wv * 128 + quad * 8;
      #pragma unroll
      for (int i = 0; i < 4; ++i) {
        short8 v;
        #pragma unroll
        for (int j = 0; j < 8; ++j) v[j] = (short)f2bf(phh[i * 32 + j]);
        bwh[g][nt][i] = v;
      }
    }
  }

  const int ew_b  = tid >> 4;          // elementwise row 0..15
  const int ew_j0 = (tid & 15) * 2;    // first of 2 adjacent owned cols
  float b_rz[2], b_zz[2], b_in[2], b_hn[2];
  #pragma unroll
  for (int e = 0; e < 2; ++e) {
    const int c = colbase + ew_j0 + e;
    b_rz[e] = b_ih[c] + b_hh[c];
    b_zz[e] = b_ih[H_DIM + c] + b_hh[H_DIM + c];
    b_in[e] = b_ih[2 * H_DIM + c];
    b_hn[e] = b_hh[2 * H_DIM + c];
  }
  float hm[2] = {0.0f, 0.0f};   // fp32 master h carry: thread-private registers

  // ---- x fp32 regs for step t (my 32-col K-slice), loaded during step t-1 ----
  floatx4 xf0, xf1;
  {
    const float* px = x + ((size_t)(bgbase + n16)) * F_DIM + wv * 32 + quad * 8;
    xf0 = *(const floatx4*)px;
    xf1 = *(const floatx4*)(px + 4);
  }

  int mguard = 1 << 18;   // shared anti-hang poll budget (bugs fail, never hang)

  for (int t = 0; t < T_LEN; ++t) {
    // ---- x-part of this step's partials (also producer-settling delay) ----
    floatx4 aR0 = {0.f,0.f,0.f,0.f}, aR1 = {0.f,0.f,0.f,0.f};
    floatx4 aZ0 = {0.f,0.f,0.f,0.f}, aZ1 = {0.f,0.f,0.f,0.f};
    floatx4 aX0 = {0.f,0.f,0.f,0.f}, aX1 = {0.f,0.f,0.f,0.f};
    floatx4 aH0 = {0.f,0.f,0.f,0.f}, aH1 = {0.f,0.f,0.f,0.f};
    {
      short8 a = cvt8(xf0, xf1);
      aR0 = __builtin_amdgcn_mfma_f32_16x16x32_bf16(a, bwx[0][0], aR0, 0, 0, 0);
      aR1 = __builtin_amdgcn_mfma_f32_16x16x32_bf16(a, bwx[0][1], aR1, 0, 0, 0);
      aZ0 = __builtin_amdgcn_mfma_f32_16x16x32_bf16(a, bwx[1][0], aZ0, 0, 0, 0);
      aZ1 = __builtin_amdgcn_mfma_f32_16x16x32_bf16(a, bwx[1][1], aZ1, 0, 0, 0);
      aX0 = __builtin_amdgcn_mfma_f32_16x16x32_bf16(a, bwx[2][0], aX0, 0, 0, 0);
      aX1 = __builtin_amdgcn_mfma_f32_16x16x32_bf16(a, bwx[2][1], aX1, 0, 0, 0);
    }

    if (t > 0) {
      // ---- direct data-poll: my K-quarter of h(t-1), the load IS the poll ----
      floatx4 hf[4];
      {
        const unsigned short* hbase =
            hs + ((size_t)((t - 1) * B_SZ + bgbase + n16)) * H_DIM + wv * 128 + quad * 8;
        while (true) {
          hload4_llc(hf, hbase);
          bool ok = true;
          #pragma unroll
          for (int i = 0; i < 4; ++i) {
            uintx4 u = __builtin_bit_cast(uintx4, hf[i]);
            ok = ok && (u[0] != SENTINEL) && (u[1] != SENTINEL) &&
                       (u[2] != SENTINEL) && (u[3] != SENTINEL);
          }
          if (__ballot(!ok) == 0ull) break;
          if (--mguard <= 0) break;
        }
      }
      // ---- issue x loads for t+1 (latency hides under h-MFMA+elementwise) ----
      if (t + 1 < T_LEN) {
        const float* px = x + ((size_t)((t + 1) * B_SZ + bgbase + n16)) * F_DIM +
                          wv * 32 + quad * 8;
        xf0 = *(const floatx4*)px;
        xf1 = *(const floatx4*)(px + 4);
      }
      // ---- h-part MFMAs over my K-quarter (r, z, hn) ----
      #pragma unroll
      for (int i = 0; i < 4; ++i) {
        short8 a = __builtin_bit_cast(short8, hf[i]);
        aR0 = __builtin_amdgcn_mfma_f32_16x16x32_bf16(a, bwh[0][0][i], aR0, 0, 0, 0);
        aR1 = __builtin_amdgcn_mfma_f32_16x16x32_bf16(a, bwh[0][1][i], aR1, 0, 0, 0);
        aZ0 = __builtin_amdgcn_mfma_f32_16x16x32_bf16(a, bwh[1][0][i], aZ0, 0, 0, 0);
        aZ1 = __builtin_amdgcn_mfma_f32_16x16x32_bf16(a, bwh[1][1][i], aZ1, 0, 0, 0);
        aH0 = __builtin_amdgcn_mfma_f32_16x16x32_bf16(a, bwh[2][0][i], aH0, 0, 0, 0);
        aH1 = __builtin_amdgcn_mfma_f32_16x16x32_bf16(a, bwh[2][1][i], aH1, 0, 0, 0);
      }
    } else {
      // t == 0: no h yet; prefetch x for t=1
      const float* px = x + ((size_t)(B_SZ + bgbase + n16)) * F_DIM + wv * 32 + quad * 8;
      xf0 = *(const floatx4*)px;
      xf1 = *(const floatx4*)(px + 4);
    }

    // ---- write my partials, b128, conflict-free layout ----
    {
      const int tb = t & 1;
      #pragma unroll
      for (int i = 0; i < 4; ++i) {
        const int r = quad * 4 + i;
        floatx4 v0 = {aR0[i], aZ0[i], aX0[i], aH0[i]};
        floatx4 v1 = {aR1[i], aZ1[i], aX1[i], aH1[i]};
        *(floatx4*)&part[tb][wv][r][n16][0]      = v0;
        *(floatx4*)&part[tb][wv][r][16 + n16][0] = v1;
      }
    }
    __syncthreads();   // the ONE barrier per step: part[t&1] ready

    // ---- fused gate elementwise: sum 4 partials; 2 (b,col) items/thread ----
    {
      const int tb = t & 1;
      float pr[2] = {0.f, 0.f}, pz[2] = {0.f, 0.f};
      float pn[2] = {0.f, 0.f}, ph[2] = {0.f, 0.f};
      #pragma unroll
      for (int w = 0; w < 4; ++w) {
        #pragma unroll
        for (int e = 0; e < 2; ++e) {
          floatx4 g = *(const floatx4*)&part[tb][w][ew_b][ew_j0 + e][0];
          pr[e] += g[0]; pz[e] += g[1]; pn[e] += g[2]; ph[e] += g[3];
        }
      }
      unsigned short hb[2];
      #pragma unroll
      for (int e = 0; e < 2; ++e) {
        const float r = sigmoidf_(pr[e] + b_rz[e]);
        const float z = sigmoidf_(pz[e] + b_zz[e]);
        const float n = tanhf_(pn[e] + b_in[e] + r * (ph[e] + b_hn[e]));
        const float hn2 = (1.0f - z) * n + z * hm[e];
        hm[e] = hn2;   // fp32 carry path in registers
        hb[e] = f2bf(hn2);
      }
      const unsigned int packed = ((unsigned int)hb[1] << 16) | (unsigned int)hb[0];
      unsigned int* dst = (unsigned int*)(hs +
          ((size_t)(t * B_SZ + bgbase + ew_b)) * H_DIM + colbase + ew_j0);
      // fire-and-forget device-scope store; consumers' data-poll absorbs latency
      __hip_atomic_store(dst, packed, __ATOMIC_RELAXED, __HIP_MEMORY_SCOPE_AGENT);
    }
    // no second barrier: partials double-buffered, h carry in registers
  }
}

// y = hs @ w_out^T + b_out : M=32768, N=16, K=512; 4 row-tiles per wg (1/wave)
__global__ __launch_bounds__(256, 1)
void gru_proj(const unsigned short* __restrict__ hs,
              const float* __restrict__ w_out,
              const float* __restrict__ b_out,
              float* __restrict__ y) {
  const int tid  = threadIdx.x;
  const int lane = tid & 63;
  const int wv   = tid >> 6;
  const int n16  = lane & 15;
  const int quad = lane >> 4;
  const size_t rowbase = ((size_t)blockIdx.x * 4 + wv) * 16;

  short8 bw[16];
  const float* pw = w_out + (size_t)n16 * H_DIM + quad * 8;
  #pragma unroll
  for (int kc = 0; kc < 16; ++kc) {
    short8 v;
    #pragma unroll
    for (int j = 0; j < 8; ++j) v[j] = (short)f2bf(pw[kc * 32 + j]);
    bw[kc] = v;
  }
  const float bo = b_out[n16];

  const unsigned short* hbase = hs + (rowbase + n16) * H_DIM + quad * 8;
  floatx4 acc = {0.f, 0.f, 0.f, 0.f};
  #pragma unroll
  for (int kc = 0; kc < 16; ++kc) {
    short8 a = *(const short8*)(hbase + kc * 32);
    acc = __builtin_amdgcn_mfma_f32_16x16x32_bf16(a, bw[kc], acc, 0, 0, 0);
  }
  #pragma unroll
  for (int i = 0; i < 4; ++i) {
    const size_t r = rowbase + quad * 4 + i;
    y[r * O_DIM + n16] = acc[i] + bo;
  }
}

extern "C" void kernel_launch(void* const* d_in, const int* in_sizes, int n_in,
                              void* d_out, int out_size, void* d_ws, size_t ws_size,
                              hipStream_t stream) {
  (void)in_sizes; (void)n_in; (void)out_size; (void)ws_size;
  const float* x     = (const float*)d_in[0];
  const float* w_ih  = (const float*)d_in[1];
  const float* w_hh  = (const float*)d_in[2];
  const float* b_ih  = (const float*)d_in[3];
  const float* b_hh  = (const float*)d_in[4];
  const float* w_out = (const float*)d_in[5];
  const float* b_out = (const float*)d_in[6];
  float* y = (float*)d_out;

  // hs: 32 MB bf16 history in d_ws. The harness poisons d_ws with 0xAA before
  // every launch — that poison IS our "not yet written" sentinel. No memset.
  unsigned short* hs = (unsigned short*)d_ws;

  gru_persistent<<<64, 256, 0, stream>>>(x, w_ih, w_hh, b_ih, b_hh, hs);
  gru_proj<<<(T_LEN * B_SZ) / 16 / 4, 256, 0, stream>>>(hs, w_out, b_out, y);
}